// Round 14
// baseline (572.643 us; speedup 1.0000x reference)
//
#include <hip/hip_runtime.h>
#include <stdint.h>

#define B_    4
#define S_    4096
#define D_    1024
#define H_    16
#define DH_   64
#define BLEN_ 256
#define FF_   4096
#define M_    16384   // B_*S_

typedef unsigned short u16;
typedef __attribute__((ext_vector_type(8))) short s8v;   // 8 x bf16 bits
typedef __attribute__((ext_vector_type(4))) short s4v;   // 4 x bf16 bits
typedef __attribute__((ext_vector_type(4))) float f4v;

#define MFMA32(A,B,C) __builtin_amdgcn_mfma_f32_16x16x32_bf16(A,B,C,0,0,0)
#define BAR() asm volatile("s_barrier" ::: "memory")

// 16x16x16 bf16 MFMA (attention PV). __has_builtin valid only in DEVICE pass.
__device__ __forceinline__ f4v mfma16(s4v a, s4v b, f4v c) {
#if defined(__HIP_DEVICE_COMPILE__)
#if __has_builtin(__builtin_amdgcn_mfma_f32_16x16x16bf16_1k)
  return __builtin_amdgcn_mfma_f32_16x16x16bf16_1k(a, b, c, 0, 0, 0);
#elif __has_builtin(__builtin_amdgcn_mfma_f32_16x16x16_bf16_1k)
  return __builtin_amdgcn_mfma_f32_16x16x16_bf16_1k(a, b, c, 0, 0, 0);
#elif __has_builtin(__builtin_amdgcn_mfma_f32_16x16x16_bf16)
  return __builtin_amdgcn_mfma_f32_16x16x16_bf16(a, b, c, 0, 0, 0);
#else
  f4v d;
  asm volatile("v_mfma_f32_16x16x16_bf16 %0, %1, %2, %3"
               : "=v"(d) : "v"(a), "v"(b), "v"(c));
  return d;
#endif
#else
  (void)a; (void)b; return c;   // host pass: parse-only
#endif
}

__device__ __forceinline__ u16 f2b(float f) {
  union { float f; unsigned u; } v; v.f = f;
  unsigned r = v.u + 0x7fffu + ((v.u >> 16) & 1u);   // RNE
  return (u16)(r >> 16);
}
__device__ __forceinline__ float b2f(u16 h) {
  union { unsigned u; float f; } v; v.u = ((unsigned)h) << 16; return v.f;
}

// async global->LDS, 16B/lane. lp wave-uniform; lane l lands at lp + l*16.
__device__ __forceinline__ void gld16(const void* gp, void* lp) {
  __builtin_amdgcn_global_load_lds(
      (const __attribute__((address_space(1))) void*)(uintptr_t)gp,
      (__attribute__((address_space(3))) void*)(uintptr_t)lp, 16, 0, 0);
}

// ---------------- elementwise prep ----------------

__global__ __launch_bounds__(256) void k_castx(const float* __restrict__ in, u16* __restrict__ out) {
  long i = (long)blockIdx.x * 256 + threadIdx.x;
  float4 v = ((const float4*)in)[i];
  s4v o; o[0] = (short)f2b(v.x); o[1] = (short)f2b(v.y);
  o[2] = (short)f2b(v.z); o[3] = (short)f2b(v.w);
  *(s4v*)(out + i * 4) = o;
}

// all six weight transposes in ONE launch: out[n*K + k] = in[k*N + n] * scale
struct WtJobs {
  const float* src[6];
  u16* dst[6];
  int K[6];
  int N[6];
  float sc[6];
  int off[7];   // cumulative block offsets
};
__global__ __launch_bounds__(256) void k_wtall(WtJobs J) {
  __shared__ u16 tile[32][33];
  const int b = blockIdx.x;
  int j = 0;
#pragma unroll
  for (int q = 0; q < 5; q++) if (b >= J.off[q + 1]) j = q + 1;
  const float* in = J.src[j];
  u16* out = J.dst[j];
  const int K = J.K[j], N = J.N[j];
  const float scale = J.sc[j];
  const int r = b - J.off[j];
  const int nb32 = N >> 5;
  const int kb = (r / nb32) << 5, nb = (r % nb32) << 5;
  const int tx = threadIdx.x & 31, ty = threadIdx.x >> 5;   // 32 x 8
#pragma unroll
  for (int rr = 0; rr < 4; rr++) {
    int row = ty + rr * 8;
    tile[row][tx] = f2b(in[(long)(kb + row) * N + nb + tx] * scale);
  }
  __syncthreads();
#pragma unroll
  for (int rr = 0; rr < 4; rr++) {
    int row = ty + rr * 8;                                  // n within tile
    out[(long)(nb + row) * K + kb + tx] = tile[tx][row];
  }
}

// ---------------- 256x256 8-phase GEMM: C = A[M,K] @ Bt[N,K]^T ----------
// (r7 verbatim — best measured: FFN 142us, MfmaUtil 43%, FETCH 148MB, 0 conflicts)
// Rasterization: nb = wg % NB (fast), mb = wg / NB -> A-panels L2-resident per XCD.
// EPI 0: bf16(acc)   1: +resf32   2: relu(+bias)   3: +bias +bf16res
template<int QM, int QN>
__device__ __forceinline__ void phmfma(f4v (&acc)[8][4], s8v (&A)[4][2], s8v (&B)[2][2]) {
#pragma unroll
  for (int mt = 0; mt < 4; mt++)
#pragma unroll
    for (int nt = 0; nt < 2; nt++) {
      acc[QM * 4 + mt][QN * 2 + nt] = MFMA32(A[mt][0], B[nt][0], acc[QM * 4 + mt][QN * 2 + nt]);
      acc[QM * 4 + mt][QN * 2 + nt] = MFMA32(A[mt][1], B[nt][1], acc[QM * 4 + mt][QN * 2 + nt]);
    }
}

#define RD_A(d, half, DST) \
  _Pragma("unroll") for (int mt = 0; mt < 4; mt++) { \
    DST[mt][0] = rdA(d, mt + (half) * 4, 0); DST[mt][1] = rdA(d, mt + (half) * 4, 1); }
#define RD_B(d, half, DST) \
  _Pragma("unroll") for (int nt = 0; nt < 2; nt++) { \
    DST[nt][0] = rdB(d, nt + (half) * 2, 0); DST[nt][1] = rdB(d, nt + (half) * 2, 1); }

#define PHASE(GATE, READS, STAGE, QM, QN, AA, BB) \
  READS STAGE \
  BAR(); \
  asm volatile("s_waitcnt lgkmcnt(0)" ::: "memory"); \
  __builtin_amdgcn_sched_barrier(0); \
  __builtin_amdgcn_s_setprio(1); \
  phmfma<QM, QN>(acc, AA, BB); \
  __builtin_amdgcn_s_setprio(0); \
  asm volatile("s_waitcnt vmcnt(" #GATE ")" ::: "memory"); \
  BAR();

template<int EPI, int K, int NB>
__global__ __launch_bounds__(512, 2) void k_gemm256(
    const u16* __restrict__ A, const u16* __restrict__ Bt,
    const float* __restrict__ bias, const void* __restrict__ res,
    u16* __restrict__ out, int N) {
  __shared__ __align__(16) u16 sA[2][16384];   // [buf][256 rows][64], XOR-swizzled
  __shared__ __align__(16) u16 sB[2][16384];
  const int t = threadIdx.x, lane = t & 63, w = t >> 6;
  const int wm = w >> 2, wn = w & 3;           // 2 x 4 waves
  const int nwg = gridDim.x, cpx = nwg >> 3, orig = blockIdx.x;
  const int wg = (orig & 7) * cpx + (orig >> 3);     // XCD swizzle (nwg % 8 == 0)
  const int nb = wg % NB, mb = wg / NB;        // nb fast -> A-panel L2-resident per XCD
  const int m0 = mb << 8, n0 = nb << 8;
  constexpr int NT = K >> 6;                   // even for all our shapes
  constexpr int NP = NT >> 1;

  const int srow = lane >> 3;
  const int scol = ((lane & 7) ^ srow) << 3;   // pre-swizzled global source (rule #21)
  const u16* gA = A + (size_t)(m0 + srow) * K + scol;
  const u16* gB = Bt + (size_t)(n0 + srow) * K + scol;

  auto stA = [&](int d, int h, int kt) {       // half-tile: 2 gld16 per wave
#pragma unroll
    for (int i = 0; i < 2; i++) {
      int c = i * 8 + w;
      gld16(gA + (size_t)(h * 128 + c * 8) * K + kt * 64, &sA[d][h * 8192 + c * 512]);
    }
  };
  auto stB = [&](int d, int h, int kt) {
#pragma unroll
    for (int i = 0; i < 2; i++) {
      int c = i * 8 + w;
      gld16(gB + (size_t)(h * 128 + c * 8) * K + kt * 64, &sB[d][h * 8192 + c * 512]);
    }
  };

  const int swz = (lane & 7) << 4;
  const int g8b = (lane >> 4) << 4;
  const int r16 = lane & 15;
  auto rdA = [&](int d, int mt, int kh) -> s8v {  // row = mt*32 + wm*16 + r16 (mt 0..7)
    int byt = (mt * 32 + wm * 16 + r16) * 128 + ((kh * 64 + g8b) ^ swz);
    return *(const s8v*)((const char*)sA[d] + byt);
  };
  auto rdB = [&](int d, int nt, int kh) -> s8v {  // row = nt*64 + wn*16 + r16 (nt 0..3)
    int byt = (nt * 64 + wn * 16 + r16) * 128 + ((kh * 64 + g8b) ^ swz);
    return *(const s8v*)((const char*)sB[d] + byt);
  };

  f4v acc[8][4];
  f4v zz = {0.f, 0.f, 0.f, 0.f};
#pragma unroll
  for (int i = 0; i < 8; i++)
#pragma unroll
    for (int j = 0; j < 4; j++) acc[i][j] = zz;

  // prologue: A0(0),B0(0),B1(0),A1(0) -> buf0; A0(1),B0(1),B1(1) -> buf1  (14 instr)
  stA(0, 0, 0); stB(0, 0, 0); stB(0, 1, 0); stA(0, 1, 0);
  stA(1, 0, 1); stB(1, 0, 1); stB(1, 1, 1);
  asm volatile("s_waitcnt vmcnt(10)" ::: "memory");   // first 4 (A0,B0 of tile0) done
  BAR();

  s8v a0[4][2], a1[4][2], bb0[2][2], bb1[2][2];

  for (int pp = 0; pp < NP - 1; ++pp) {
    const int j = pp * 2;
    // tile j (buf0)
    PHASE(10, RD_A(0, 0, a0) RD_B(0, 0, bb0), stA(1, 1, j + 1);, 0, 0, a0, bb0)
    PHASE(10, RD_B(0, 1, bb1),                stA(0, 0, j + 2);, 0, 1, a0, bb1)
    PHASE(10, RD_A(0, 1, a1),                 stB(0, 0, j + 2);, 1, 0, a1, bb0)
    PHASE(10, ,                               stB(0, 1, j + 2);, 1, 1, a1, bb1)
    // tile j+1 (buf1)
    PHASE(10, RD_A(1, 0, a0) RD_B(1, 0, bb0), stA(0, 1, j + 2);, 0, 0, a0, bb0)
    PHASE(10, RD_B(1, 1, bb1),                stA(1, 0, j + 3);, 0, 1, a0, bb1)
    PHASE(10, RD_A(1, 1, a1),                 stB(1, 0, j + 3);, 1, 0, a1, bb0)
    PHASE(10, ,                               stB(1, 1, j + 3);, 1, 1, a1, bb1)
  }
  // peeled last pair (j = NT-2): stage only A1(NT-1); drain ladder
  PHASE(10, RD_A(0, 0, a0) RD_B(0, 0, bb0), stA(1, 1, NT - 1);, 0, 0, a0, bb0)
  PHASE(8,  RD_B(0, 1, bb1),                ,                   0, 1, a0, bb1)
  PHASE(8,  RD_A(0, 1, a1),                 ,                   1, 0, a1, bb0)
  PHASE(4,  ,                               ,                   1, 1, a1, bb1)
  PHASE(2,  RD_A(1, 0, a0) RD_B(1, 0, bb0), ,                   0, 0, a0, bb0)
  PHASE(0,  RD_B(1, 1, bb1),                ,                   0, 1, a0, bb1)
  PHASE(0,  RD_A(1, 1, a1),                 ,                   1, 0, a1, bb0)
  PHASE(0,  ,                               ,                   1, 1, a1, bb1)

  // epilogue: acc[mt][nt][r] -> row m0+mt*32+wm*16+g4+r, col n0+nt*64+wn*16+r16
  const int g4 = (lane >> 4) << 2;
#pragma unroll
  for (int mt = 0; mt < 8; mt++) {
#pragma unroll
    for (int nt = 0; nt < 4; nt++) {
      const int col = n0 + nt * 64 + wn * 16 + r16;
      const long rbase = m0 + mt * 32 + wm * 16 + g4;
      float bcol = 0.f;
      if constexpr (EPI == 2 || EPI == 3) bcol = bias[col];
#pragma unroll
      for (int r = 0; r < 4; r++) {
        long idx = (rbase + r) * (long)N + col;
        float v = acc[mt][nt][r];
        if constexpr (EPI == 1) v += ((const float*)res)[idx];
        if constexpr (EPI == 2) { v += bcol; v = fmaxf(v, 0.f); }
        if constexpr (EPI == 3) { v += bcol + b2f(((const u16*)res)[idx]); }
        out[idx] = f2b(v);
      }
    }
  }
}

// ---------------- block-local attention (QKV fused buffer, row stride 3072) -----------
// r13 structure, but each 64-key chunk is processed as two 32-key halves through the
// online softmax: st shrinks [4][4]->[2][4], pf [4][4]->[4][2] => live VGPR ~124,
// targeting 16 waves/CU (4 blocks) instead of 12. Math identical (online-softmax
// associativity). Staging/barriers untouched.
__global__ __launch_bounds__(256) void k_attn(const u16* __restrict__ QKV, u16* __restrict__ Aout) {
  __shared__ __align__(16) u16 sK[64 * 64];    // [key][dh], byte ^ ((key&7)<<4)
  __shared__ __align__(16) u16 sVT[64 * 64];   // [dh][key], byte ^ ((dh&7)<<3)
  const int t = threadIdx.x, lane = t & 63, w = t >> 6;
  const int qblock = blockIdx.x;
  const int b = blockIdx.y >> 4, h = blockIdx.y & 15;
  const int qcol = lane & 15, g = lane >> 4, g4 = g << 2;
  const int win = (qblock == 0) ? 0 : (qblock - 1) * BLEN_;
  const int nch = (qblock == 0) ? 4 : 8;
  const int qbw = qblock * BLEN_ + w * 64;
  const long rowbase = (long)b * S_;
  const int LDQ = 3072;

  s8v qf[4][2];
#pragma unroll
  for (int nt = 0; nt < 4; nt++)
#pragma unroll
    for (int kh = 0; kh < 2; kh++)
      qf[nt][kh] = *(const s8v*)(QKV + (rowbase + qbw + nt * 16 + qcol) * LDQ + h * DH_ + kh * 32 + (g << 3));

  f4v zz = {0.f, 0.f, 0.f, 0.f};
  f4v acc[4][4];
#pragma unroll
  for (int i = 0; i < 4; i++)
#pragma unroll
    for (int j = 0; j < 4; j++) acc[i][j] = zz;
  float mrow[4] = {-1e30f, -1e30f, -1e30f, -1e30f};
  float lrow[4] = {0.f, 0.f, 0.f, 0.f};

  for (int c = 0; c < nch; ++c) {
    const int kb = win + c * 64;
    __syncthreads();
#pragma unroll
    for (int p = 0; p < 2; p++) {
      int key = p * 32 + (t >> 3);
      int d8 = (t & 7) << 3;
      s8v kv = *(const s8v*)(QKV + (rowbase + kb + key) * LDQ + 1024 + h * DH_ + d8);
      int bo = key * 128 + d8 * 2; bo ^= (key & 7) << 4;
      *(s8v*)((char*)sK + bo) = kv;
    }
#pragma unroll
    for (int p = 0; p < 2; p++) {
      int key = (t & 31) + (p << 5);
      int d8 = (t >> 5) << 3;
      s8v vv = *(const s8v*)(QKV + (rowbase + kb + key) * LDQ + 2048 + h * DH_ + d8);
#pragma unroll
      for (int j = 0; j < 8; j++) {
        int dh = d8 + j;
        int bo = dh * 128 + key * 2; bo ^= (dh & 7) << 3;
        *(u16*)((char*)sVT + bo) = (u16)vv[j];
      }
    }
    __syncthreads();
    if (kb > qbw + 63) continue;

#pragma unroll
    for (int h2 = 0; h2 < 2; h2++) {
      const int kb2 = kb + h2 * 32;
      if (kb2 > qbw + 63) break;              // uniform (qbw wave-uniform); h2=0 never breaks

      // S^T for this 32-key half: st[mt2][nt], mt = h2*2 + mt2
      f4v st[2][4];
#pragma unroll
      for (int i = 0; i < 2; i++)
#pragma unroll
        for (int j = 0; j < 4; j++) st[i][j] = zz;
#pragma unroll
      for (int kh = 0; kh < 2; kh++) {
#pragma unroll
        for (int mt2 = 0; mt2 < 2; mt2++) {
          int key = (h2 * 2 + mt2) * 16 + qcol;
          int bo = key * 128 + kh * 64 + (g << 4); bo ^= (key & 7) << 4;
          s8v kf = *(const s8v*)((const char*)sK + bo);
#pragma unroll
          for (int nt = 0; nt < 4; nt++) st[mt2][nt] = MFMA32(kf, qf[nt][kh], st[mt2][nt]);
        }
      }
      if (kb2 + 31 > qbw) {                   // causal mask within half
#pragma unroll
        for (int mt2 = 0; mt2 < 2; mt2++) {
          int kbase = kb2 + mt2 * 16 + g4;
#pragma unroll
          for (int nt = 0; nt < 4; nt++) {
            int qabs = qbw + nt * 16 + qcol;
#pragma unroll
            for (int r = 0; r < 4; r++)
              if (kbase + r > qabs) st[mt2][nt][r] = -1e30f;
          }
        }
      }
      // online softmax update for this half
      s4v pf[4][2];
#pragma unroll
      for (int nt = 0; nt < 4; nt++) {
        float cm = -1e30f;
#pragma unroll
        for (int mt2 = 0; mt2 < 2; mt2++)
#pragma unroll
          for (int r = 0; r < 4; r++) cm = fmaxf(cm, st[mt2][nt][r]);
        cm = fmaxf(cm, __shfl_xor(cm, 16));
        cm = fmaxf(cm, __shfl_xor(cm, 32));
        float mnew = fmaxf(mrow[nt], cm);
        float sc = __expf(mrow[nt] - mnew);
        mrow[nt] = mnew;
        float ps = 0.f;
#pragma unroll
        for (int kt2 = 0; kt2 < 2; kt2++) {
          s4v pp;
#pragma unroll
          for (int r = 0; r < 4; r++) {
            float p = __expf(st[kt2][nt][r] - mnew);   // masked (-1e30) underflows to 0
            ps += p;
            pp[r] = (short)f2b(p);
          }
          pf[nt][kt2] = pp;
        }
        ps += __shfl_xor(ps, 16);
        ps += __shfl_xor(ps, 32);
        lrow[nt] = lrow[nt] * sc + ps;
#pragma unroll
        for (int dt = 0; dt < 4; dt++) acc[dt][nt] *= sc;
      }
      // O^T += V^T(half) @ P^T(half)
#pragma unroll
      for (int dt = 0; dt < 4; dt++) {
        int dh = dt * 16 + qcol;
#pragma unroll
        for (int kt2 = 0; kt2 < 2; kt2++) {
          int kt = h2 * 2 + kt2;
          int bo = dh * 128 + kt * 32 + (g << 3); bo ^= (dh & 7) << 3;
          s4v vf = *(const s4v*)((const char*)sVT + bo);
#pragma unroll
          for (int nt = 0; nt < 4; nt++) acc[dt][nt] = mfma16(vf, pf[nt][kt2], acc[dt][nt]);
        }
      }
    }
  }

#pragma unroll
  for (int nt = 0; nt < 4; nt++) {
    float inv = 1.f / lrow[nt];
    long qrow = rowbase + qbw + nt * 16 + qcol;
#pragma unroll
    for (int dt = 0; dt < 4; dt++) {
      s4v o;
#pragma unroll
      for (int r = 0; r < 4; r++) o[r] = (short)f2b(acc[dt][nt][r] * inv);
      *(s4v*)(Aout + qrow * D_ + h * DH_ + dt * 16 + g4) = o;
    }
  }
}

// ---------------- LayerNorm over D=1024, one row per block ----------------
template<int OUTB>
__global__ __launch_bounds__(256) void k_ln(const u16* __restrict__ in, const float* __restrict__ gw,
                                            const float* __restrict__ bw, float* __restrict__ outf,
                                            u16* __restrict__ outb) {
  const int t = threadIdx.x, lane = t & 63, w = t >> 6;
  const long base = (long)blockIdx.x * D_;
  s4v xv = *(const s4v*)(in + base + t * 4);
  float v0 = b2f((u16)xv[0]), v1 = b2f((u16)xv[1]), v2 = b2f((u16)xv[2]), v3 = b2f((u16)xv[3]);
  float s = v0 + v1 + v2 + v3;
  float s2 = v0 * v0 + v1 * v1 + v2 * v2 + v3 * v3;
#pragma unroll
  for (int off = 1; off < 64; off <<= 1) { s += __shfl_xor(s, off); s2 += __shfl_xor(s2, off); }
  __shared__ float red[8];
  if (lane == 0) { red[w] = s; red[4 + w] = s2; }
  __syncthreads();
  s = red[0] + red[1] + red[2] + red[3];
  s2 = red[4] + red[5] + red[6] + red[7];
  float mu = s * (1.f / D_);
  float var = s2 * (1.f / D_) - mu * mu;
  float rstd = rsqrtf(var + 1e-6f);
  float4 gv = ((const float4*)gw)[t];
  float4 bv = ((const float4*)bw)[t];
  float o0 = (v0 - mu) * rstd * gv.x + bv.x;
  float o1 = (v1 - mu) * rstd * gv.y + bv.y;
  float o2 = (v2 - mu) * rstd * gv.z + bv.z;
  float o3 = (v3 - mu) * rstd * gv.w + bv.w;
  if constexpr (OUTB) {
    s4v o; o[0] = (short)f2b(o0); o[1] = (short)f2b(o1); o[2] = (short)f2b(o2); o[3] = (short)f2b(o3);
    *(s4v*)(outb + base + t * 4) = o;
  } else {
    float4 o; o.x = o0; o.y = o1; o.z = o2; o.w = o3;
    *(float4*)(outf + base + t * 4) = o;
  }
}

// ---------------- host ----------------

extern "C" void kernel_launch(void* const* d_in, const int* in_sizes, int n_in,
                              void* d_out, int out_size, void* d_ws, size_t ws_size,
                              hipStream_t stream) {
  const float* X      = (const float*)d_in[0];
  const float* Wq     = (const float*)d_in[1];
  const float* Wk     = (const float*)d_in[2];
  const float* Wv     = (const float*)d_in[3];
  const float* Wo     = (const float*)d_in[4];
  const float* g_attn = (const float*)d_in[5];
  const float* b_attn = (const float*)d_in[6];
  const float* W1     = (const float*)d_in[7];
  const float* b1     = (const float*)d_in[8];
  const float* W2     = (const float*)d_in[9];
  const float* b2     = (const float*)d_in[10];
  const float* g_ffn  = (const float*)d_in[11];
  const float* b_ffn  = (const float*)d_in[12];
  float* out = (float*)d_out;

  char* ws = (char*)d_ws;
  const size_t MB = 1ull << 20;
  u16* WqkvT = (u16*)(ws + 0 * MB);    // [3072][1024] bf16 (Wq|Wk|Wv transposed)
  u16* WoT   = (u16*)(ws + 6 * MB);    // [1024][1024]
  u16* W1T   = (u16*)(ws + 8 * MB);    // [4096][1024]
  u16* W2T   = (u16*)(ws + 16 * MB);   // [1024][4096]
  u16* Xb    = (u16*)(ws + 24 * MB);   // X bf16; later X1b
  u16* QKVb  = (u16*)(ws + 56 * MB);   // [16384][3072] = 96MB
  u16* Ab    = (u16*)(ws + 152 * MB);  // [16384][1024] = 32MB
  u16* Yb    = (u16*)(ws + 184 * MB);  // pre-LN buffers; end 216MB
  u16* Mid   = QKVb;                   // [16384][4096] = 128MB, reuses QKVb+Ab

  dim3 b256(256), b512(512);

  // single-launch weight prep (Wq gets DH^-0.5 = 0.125 folded in)
  WtJobs J;
  J.src[0] = Wq; J.src[1] = Wk; J.src[2] = Wv; J.src[3] = Wo; J.src[4] = W1; J.src[5] = W2;
  J.dst[0] = WqkvT; J.dst[1] = WqkvT + 1024 * 1024; J.dst[2] = WqkvT + 2048 * 1024;
  J.dst[3] = WoT; J.dst[4] = W1T; J.dst[5] = W2T;
  J.K[0] = 1024; J.K[1] = 1024; J.K[2] = 1024; J.K[3] = 1024; J.K[4] = 1024; J.K[5] = 4096;
  J.N[0] = 1024; J.N[1] = 1024; J.N[2] = 1024; J.N[3] = 1024; J.N[4] = 4096; J.N[5] = 1024;
  J.sc[0] = 0.125f; J.sc[1] = 1.f; J.sc[2] = 1.f; J.sc[3] = 1.f; J.sc[4] = 1.f; J.sc[5] = 1.f;
  J.off[0] = 0; J.off[1] = 1024; J.off[2] = 2048; J.off[3] = 3072;
  J.off[4] = 4096; J.off[5] = 8192; J.off[6] = 12288;
  k_wtall<<<dim3(12288), b256, 0, stream>>>(J);
  k_castx<<<dim3(16384), b256, 0, stream>>>(X, Xb);

  // fused QKV projection: [16384][3072]  (NB = 12)
  k_gemm256<0, 1024, 12><<<dim3(768), b512, 0, stream>>>(Xb, WqkvT, nullptr, nullptr, QKVb, 3072);
  // block-local attention
  k_attn<<<dim3(16, B_ * H_), b256, 0, stream>>>(QKVb, Ab);
  // Wo projection + residual X  (NB = 4)
  k_gemm256<1, 1024, 4><<<dim3(256), b512, 0, stream>>>(Ab, WoT, nullptr, X, Yb, 1024);
  // LN1 -> X1 (bf16)
  k_ln<1><<<dim3(16384), b256, 0, stream>>>(Yb, g_attn, b_attn, nullptr, Xb);
  // FFN1: relu(X1@W1 + b1)  (NB = 16)
  k_gemm256<2, 1024, 16><<<dim3(1024), b512, 0, stream>>>(Xb, W1T, b1, nullptr, Mid, 4096);
  // FFN2: Mid@W2 + b2 + X1  (NB = 4)
  k_gemm256<3, 4096, 4><<<dim3(256), b512, 0, stream>>>(Mid, W2T, b2, Xb, Yb, 1024);
  // LN2 -> out (f32)
  k_ln<0><<<dim3(16384), b256, 0, stream>>>(Yb, g_ffn, b_ffn, out, nullptr);

  (void)in_sizes; (void)n_in; (void)out_size; (void)ws_size;
}

// Round 15
// 560.689 us; speedup vs baseline: 1.0213x; 1.0213x over previous
//
#include <hip/hip_runtime.h>
#include <stdint.h>

#define B_    4
#define S_    4096
#define D_    1024
#define H_    16
#define DH_   64
#define BLEN_ 256
#define FF_   4096
#define M_    16384   // B_*S_

typedef unsigned short u16;
typedef __attribute__((ext_vector_type(8))) short s8v;   // 8 x bf16 bits
typedef __attribute__((ext_vector_type(4))) short s4v;   // 4 x bf16 bits
typedef __attribute__((ext_vector_type(4))) float f4v;

#define MFMA32(A,B,C) __builtin_amdgcn_mfma_f32_16x16x32_bf16(A,B,C,0,0,0)
#define BAR() asm volatile("s_barrier" ::: "memory")

// 16x16x16 bf16 MFMA (attention PV). __has_builtin valid only in DEVICE pass.
__device__ __forceinline__ f4v mfma16(s4v a, s4v b, f4v c) {
#if defined(__HIP_DEVICE_COMPILE__)
#if __has_builtin(__builtin_amdgcn_mfma_f32_16x16x16bf16_1k)
  return __builtin_amdgcn_mfma_f32_16x16x16bf16_1k(a, b, c, 0, 0, 0);
#elif __has_builtin(__builtin_amdgcn_mfma_f32_16x16x16_bf16_1k)
  return __builtin_amdgcn_mfma_f32_16x16x16_bf16_1k(a, b, c, 0, 0, 0);
#elif __has_builtin(__builtin_amdgcn_mfma_f32_16x16x16_bf16)
  return __builtin_amdgcn_mfma_f32_16x16x16_bf16(a, b, c, 0, 0, 0);
#else
  f4v d;
  asm volatile("v_mfma_f32_16x16x16_bf16 %0, %1, %2, %3"
               : "=v"(d) : "v"(a), "v"(b), "v"(c));
  return d;
#endif
#else
  (void)a; (void)b; return c;   // host pass: parse-only
#endif
}

__device__ __forceinline__ u16 f2b(float f) {
  union { float f; unsigned u; } v; v.f = f;
  unsigned r = v.u + 0x7fffu + ((v.u >> 16) & 1u);   // RNE
  return (u16)(r >> 16);
}
__device__ __forceinline__ float b2f(u16 h) {
  union { unsigned u; float f; } v; v.u = ((unsigned)h) << 16; return v.f;
}

// async global->LDS, 16B/lane. lp wave-uniform; lane l lands at lp + l*16.
__device__ __forceinline__ void gld16(const void* gp, void* lp) {
  __builtin_amdgcn_global_load_lds(
      (const __attribute__((address_space(1))) void*)(uintptr_t)gp,
      (__attribute__((address_space(3))) void*)(uintptr_t)lp, 16, 0, 0);
}

// ---------------- elementwise prep ----------------

__global__ __launch_bounds__(256) void k_castx(const float* __restrict__ in, u16* __restrict__ out) {
  long i = (long)blockIdx.x * 256 + threadIdx.x;
  float4 v = ((const float4*)in)[i];
  s4v o; o[0] = (short)f2b(v.x); o[1] = (short)f2b(v.y);
  o[2] = (short)f2b(v.z); o[3] = (short)f2b(v.w);
  *(s4v*)(out + i * 4) = o;
}

// all six weight transposes in ONE launch: out[n*K + k] = in[k*N + n] * scale
struct WtJobs {
  const float* src[6];
  u16* dst[6];
  int K[6];
  int N[6];
  float sc[6];
  int off[7];   // cumulative block offsets
};
__global__ __launch_bounds__(256) void k_wtall(WtJobs J) {
  __shared__ u16 tile[32][33];
  const int b = blockIdx.x;
  int j = 0;
#pragma unroll
  for (int q = 0; q < 5; q++) if (b >= J.off[q + 1]) j = q + 1;
  const float* in = J.src[j];
  u16* out = J.dst[j];
  const int K = J.K[j], N = J.N[j];
  const float scale = J.sc[j];
  const int r = b - J.off[j];
  const int nb32 = N >> 5;
  const int kb = (r / nb32) << 5, nb = (r % nb32) << 5;
  const int tx = threadIdx.x & 31, ty = threadIdx.x >> 5;   // 32 x 8
#pragma unroll
  for (int rr = 0; rr < 4; rr++) {
    int row = ty + rr * 8;
    tile[row][tx] = f2b(in[(long)(kb + row) * N + nb + tx] * scale);
  }
  __syncthreads();
#pragma unroll
  for (int rr = 0; rr < 4; rr++) {
    int row = ty + rr * 8;                                  // n within tile
    out[(long)(nb + row) * K + kb + tx] = tile[tx][row];
  }
}

// ---------------- 256x256 8-phase GEMM: C = A[M,K] @ Bt[N,K]^T ----------
// (r7 verbatim — best measured: FFN 142us, MfmaUtil 43%, FETCH 148MB, 0 conflicts)
// Rasterization: nb = wg % NB (fast), mb = wg / NB -> A-panels L2-resident per XCD.
// EPI 0: bf16(acc)   1: +bf16res   2: relu(+bias)   3: +bias +bf16res
template<int QM, int QN>
__device__ __forceinline__ void phmfma(f4v (&acc)[8][4], s8v (&A)[4][2], s8v (&B)[2][2]) {
#pragma unroll
  for (int mt = 0; mt < 4; mt++)
#pragma unroll
    for (int nt = 0; nt < 2; nt++) {
      acc[QM * 4 + mt][QN * 2 + nt] = MFMA32(A[mt][0], B[nt][0], acc[QM * 4 + mt][QN * 2 + nt]);
      acc[QM * 4 + mt][QN * 2 + nt] = MFMA32(A[mt][1], B[nt][1], acc[QM * 4 + mt][QN * 2 + nt]);
    }
}

#define RD_A(d, half, DST) \
  _Pragma("unroll") for (int mt = 0; mt < 4; mt++) { \
    DST[mt][0] = rdA(d, mt + (half) * 4, 0); DST[mt][1] = rdA(d, mt + (half) * 4, 1); }
#define RD_B(d, half, DST) \
  _Pragma("unroll") for (int nt = 0; nt < 2; nt++) { \
    DST[nt][0] = rdB(d, nt + (half) * 2, 0); DST[nt][1] = rdB(d, nt + (half) * 2, 1); }

#define PHASE(GATE, READS, STAGE, QM, QN, AA, BB) \
  READS STAGE \
  BAR(); \
  asm volatile("s_waitcnt lgkmcnt(0)" ::: "memory"); \
  __builtin_amdgcn_sched_barrier(0); \
  __builtin_amdgcn_s_setprio(1); \
  phmfma<QM, QN>(acc, AA, BB); \
  __builtin_amdgcn_s_setprio(0); \
  asm volatile("s_waitcnt vmcnt(" #GATE ")" ::: "memory"); \
  BAR();

template<int EPI, int K, int NB>
__global__ __launch_bounds__(512, 2) void k_gemm256(
    const u16* __restrict__ A, const u16* __restrict__ Bt,
    const float* __restrict__ bias, const void* __restrict__ res,
    u16* __restrict__ out, int N) {
  __shared__ __align__(16) u16 sA[2][16384];   // [buf][256 rows][64], XOR-swizzled
  __shared__ __align__(16) u16 sB[2][16384];
  const int t = threadIdx.x, lane = t & 63, w = t >> 6;
  const int wm = w >> 2, wn = w & 3;           // 2 x 4 waves
  const int nwg = gridDim.x, cpx = nwg >> 3, orig = blockIdx.x;
  const int wg = (orig & 7) * cpx + (orig >> 3);     // XCD swizzle (nwg % 8 == 0)
  const int nb = wg % NB, mb = wg / NB;        // nb fast -> A-panel L2-resident per XCD
  const int m0 = mb << 8, n0 = nb << 8;
  constexpr int NT = K >> 6;                   // even for all our shapes
  constexpr int NP = NT >> 1;

  const int srow = lane >> 3;
  const int scol = ((lane & 7) ^ srow) << 3;   // pre-swizzled global source (rule #21)
  const u16* gA = A + (size_t)(m0 + srow) * K + scol;
  const u16* gB = Bt + (size_t)(n0 + srow) * K + scol;

  auto stA = [&](int d, int h, int kt) {       // half-tile: 2 gld16 per wave
#pragma unroll
    for (int i = 0; i < 2; i++) {
      int c = i * 8 + w;
      gld16(gA + (size_t)(h * 128 + c * 8) * K + kt * 64, &sA[d][h * 8192 + c * 512]);
    }
  };
  auto stB = [&](int d, int h, int kt) {
#pragma unroll
    for (int i = 0; i < 2; i++) {
      int c = i * 8 + w;
      gld16(gB + (size_t)(h * 128 + c * 8) * K + kt * 64, &sB[d][h * 8192 + c * 512]);
    }
  };

  const int swz = (lane & 7) << 4;
  const int g8b = (lane >> 4) << 4;
  const int r16 = lane & 15;
  auto rdA = [&](int d, int mt, int kh) -> s8v {  // row = mt*32 + wm*16 + r16 (mt 0..7)
    int byt = (mt * 32 + wm * 16 + r16) * 128 + ((kh * 64 + g8b) ^ swz);
    return *(const s8v*)((const char*)sA[d] + byt);
  };
  auto rdB = [&](int d, int nt, int kh) -> s8v {  // row = nt*64 + wn*16 + r16 (nt 0..3)
    int byt = (nt * 64 + wn * 16 + r16) * 128 + ((kh * 64 + g8b) ^ swz);
    return *(const s8v*)((const char*)sB[d] + byt);
  };

  f4v acc[8][4];
  f4v zz = {0.f, 0.f, 0.f, 0.f};
#pragma unroll
  for (int i = 0; i < 8; i++)
#pragma unroll
    for (int j = 0; j < 4; j++) acc[i][j] = zz;

  // prologue: A0(0),B0(0),B1(0),A1(0) -> buf0; A0(1),B0(1),B1(1) -> buf1  (14 instr)
  stA(0, 0, 0); stB(0, 0, 0); stB(0, 1, 0); stA(0, 1, 0);
  stA(1, 0, 1); stB(1, 0, 1); stB(1, 1, 1);
  asm volatile("s_waitcnt vmcnt(10)" ::: "memory");   // first 4 (A0,B0 of tile0) done
  BAR();

  s8v a0[4][2], a1[4][2], bb0[2][2], bb1[2][2];

  for (int pp = 0; pp < NP - 1; ++pp) {
    const int j = pp * 2;
    // tile j (buf0)
    PHASE(10, RD_A(0, 0, a0) RD_B(0, 0, bb0), stA(1, 1, j + 1);, 0, 0, a0, bb0)
    PHASE(10, RD_B(0, 1, bb1),                stA(0, 0, j + 2);, 0, 1, a0, bb1)
    PHASE(10, RD_A(0, 1, a1),                 stB(0, 0, j + 2);, 1, 0, a1, bb0)
    PHASE(10, ,                               stB(0, 1, j + 2);, 1, 1, a1, bb1)
    // tile j+1 (buf1)
    PHASE(10, RD_A(1, 0, a0) RD_B(1, 0, bb0), stA(0, 1, j + 2);, 0, 0, a0, bb0)
    PHASE(10, RD_B(1, 1, bb1),                stA(1, 0, j + 3);, 0, 1, a0, bb1)
    PHASE(10, RD_A(1, 1, a1),                 stB(1, 0, j + 3);, 1, 0, a1, bb0)
    PHASE(10, ,                               stB(1, 1, j + 3);, 1, 1, a1, bb1)
  }
  // peeled last pair (j = NT-2): stage only A1(NT-1); drain ladder
  PHASE(10, RD_A(0, 0, a0) RD_B(0, 0, bb0), stA(1, 1, NT - 1);, 0, 0, a0, bb0)
  PHASE(8,  RD_B(0, 1, bb1),                ,                   0, 1, a0, bb1)
  PHASE(8,  RD_A(0, 1, a1),                 ,                   1, 0, a1, bb0)
  PHASE(4,  ,                               ,                   1, 1, a1, bb1)
  PHASE(2,  RD_A(1, 0, a0) RD_B(1, 0, bb0), ,                   0, 0, a0, bb0)
  PHASE(0,  RD_B(1, 1, bb1),                ,                   0, 1, a0, bb1)
  PHASE(0,  RD_A(1, 1, a1),                 ,                   1, 0, a1, bb0)
  PHASE(0,  ,                               ,                   1, 1, a1, bb1)

  // epilogue: acc[mt][nt][r] -> row m0+mt*32+wm*16+g4+r, col n0+nt*64+wn*16+r16
  const int g4 = (lane >> 4) << 2;
#pragma unroll
  for (int mt = 0; mt < 8; mt++) {
#pragma unroll
    for (int nt = 0; nt < 4; nt++) {
      const int col = n0 + nt * 64 + wn * 16 + r16;
      const long rbase = m0 + mt * 32 + wm * 16 + g4;
      float bcol = 0.f;
      if constexpr (EPI == 2 || EPI == 3) bcol = bias[col];
#pragma unroll
      for (int r = 0; r < 4; r++) {
        long idx = (rbase + r) * (long)N + col;
        float v = acc[mt][nt][r];
        if constexpr (EPI == 1) v += b2f(((const u16*)res)[idx]);
        if constexpr (EPI == 2) { v += bcol; v = fmaxf(v, 0.f); }
        if constexpr (EPI == 3) { v += bcol + b2f(((const u16*)res)[idx]); }
        out[idx] = f2b(v);
      }
    }
  }
}

// ---------------- block-local attention (QKV fused buffer, row stride 3072) -----------
// r13 structure (best measured), natural register budget.
// Masked exp via underflow: st = -1e30 -> expf gives exact 0.
__global__ __launch_bounds__(256) void k_attn(const u16* __restrict__ QKV, u16* __restrict__ Aout) {
  __shared__ __align__(16) u16 sK[64 * 64];    // [key][dh], byte ^ ((key&7)<<4)
  __shared__ __align__(16) u16 sVT[64 * 64];   // [dh][key], byte ^ ((dh&7)<<3)
  const int t = threadIdx.x, lane = t & 63, w = t >> 6;
  const int qblock = blockIdx.x;
  const int b = blockIdx.y >> 4, h = blockIdx.y & 15;
  const int qcol = lane & 15, g = lane >> 4, g4 = g << 2;
  const int win = (qblock == 0) ? 0 : (qblock - 1) * BLEN_;
  const int nch = (qblock == 0) ? 4 : 8;
  const int qbw = qblock * BLEN_ + w * 64;
  const long rowbase = (long)b * S_;
  const int LDQ = 3072;

  s8v qf[4][2];
#pragma unroll
  for (int nt = 0; nt < 4; nt++)
#pragma unroll
    for (int kh = 0; kh < 2; kh++)
      qf[nt][kh] = *(const s8v*)(QKV + (rowbase + qbw + nt * 16 + qcol) * LDQ + h * DH_ + kh * 32 + (g << 3));

  f4v zz = {0.f, 0.f, 0.f, 0.f};
  f4v acc[4][4];
#pragma unroll
  for (int i = 0; i < 4; i++)
#pragma unroll
    for (int j = 0; j < 4; j++) acc[i][j] = zz;
  float mrow[4] = {-1e30f, -1e30f, -1e30f, -1e30f};
  float lrow[4] = {0.f, 0.f, 0.f, 0.f};

  for (int c = 0; c < nch; ++c) {
    const int kb = win + c * 64;
    __syncthreads();
#pragma unroll
    for (int p = 0; p < 2; p++) {
      int key = p * 32 + (t >> 3);
      int d8 = (t & 7) << 3;
      s8v kv = *(const s8v*)(QKV + (rowbase + kb + key) * LDQ + 1024 + h * DH_ + d8);
      int bo = key * 128 + d8 * 2; bo ^= (key & 7) << 4;
      *(s8v*)((char*)sK + bo) = kv;
    }
#pragma unroll
    for (int p = 0; p < 2; p++) {
      int key = (t & 31) + (p << 5);
      int d8 = (t >> 5) << 3;
      s8v vv = *(const s8v*)(QKV + (rowbase + kb + key) * LDQ + 2048 + h * DH_ + d8);
#pragma unroll
      for (int j = 0; j < 8; j++) {
        int dh = d8 + j;
        int bo = dh * 128 + key * 2; bo ^= (dh & 7) << 3;
        *(u16*)((char*)sVT + bo) = (u16)vv[j];
      }
    }
    __syncthreads();
    if (kb > qbw + 63) continue;

    f4v st[4][4];
#pragma unroll
    for (int i = 0; i < 4; i++)
#pragma unroll
      for (int j = 0; j < 4; j++) st[i][j] = zz;
#pragma unroll
    for (int kh = 0; kh < 2; kh++) {
#pragma unroll
      for (int mt = 0; mt < 4; mt++) {
        int key = mt * 16 + qcol;
        int bo = key * 128 + kh * 64 + (g << 4); bo ^= (key & 7) << 4;
        s8v kf = *(const s8v*)((const char*)sK + bo);
#pragma unroll
        for (int nt = 0; nt < 4; nt++) st[mt][nt] = MFMA32(kf, qf[nt][kh], st[mt][nt]);
      }
    }
    if (kb + 63 > qbw) {
#pragma unroll
      for (int mt = 0; mt < 4; mt++) {
        int kbase = kb + mt * 16 + g4;
#pragma unroll
        for (int nt = 0; nt < 4; nt++) {
          int qabs = qbw + nt * 16 + qcol;
#pragma unroll
          for (int r = 0; r < 4; r++)
            if (kbase + r > qabs) st[mt][nt][r] = -1e30f;
        }
      }
    }
    s4v pf[4][4];
#pragma unroll
    for (int nt = 0; nt < 4; nt++) {
      float cm = -1e30f;
#pragma unroll
      for (int mt = 0; mt < 4; mt++)
#pragma unroll
        for (int r = 0; r < 4; r++) cm = fmaxf(cm, st[mt][nt][r]);
      cm = fmaxf(cm, __shfl_xor(cm, 16));
      cm = fmaxf(cm, __shfl_xor(cm, 32));
      float mnew = fmaxf(mrow[nt], cm);
      float sc = __expf(mrow[nt] - mnew);
      mrow[nt] = mnew;
      float ps = 0.f;
#pragma unroll
      for (int kt = 0; kt < 4; kt++) {
        s4v pp;
#pragma unroll
        for (int r = 0; r < 4; r++) {
          float p = __expf(st[kt][nt][r] - mnew);   // masked (-1e30) underflows to 0
          ps += p;
          pp[r] = (short)f2b(p);
        }
        pf[nt][kt] = pp;
      }
      ps += __shfl_xor(ps, 16);
      ps += __shfl_xor(ps, 32);
      lrow[nt] = lrow[nt] * sc + ps;
#pragma unroll
      for (int dt = 0; dt < 4; dt++) acc[dt][nt] *= sc;
    }
#pragma unroll
    for (int dt = 0; dt < 4; dt++) {
      int dh = dt * 16 + qcol;
#pragma unroll
      for (int kt = 0; kt < 4; kt++) {
        int bo = dh * 128 + kt * 32 + (g << 3); bo ^= (dh & 7) << 3;
        s4v vf = *(const s4v*)((const char*)sVT + bo);
#pragma unroll
        for (int nt = 0; nt < 4; nt++) acc[dt][nt] = mfma16(vf, pf[nt][kt], acc[dt][nt]);
      }
    }
  }

#pragma unroll
  for (int nt = 0; nt < 4; nt++) {
    float inv = 1.f / lrow[nt];
    long qrow = rowbase + qbw + nt * 16 + qcol;
#pragma unroll
    for (int dt = 0; dt < 4; dt++) {
      s4v o;
#pragma unroll
      for (int r = 0; r < 4; r++) o[r] = (short)f2b(acc[dt][nt][r] * inv);
      *(s4v*)(Aout + qrow * D_ + h * DH_ + dt * 16 + g4) = o;
    }
  }
}

// ---------------- LayerNorm over D=1024, one row per block ----------------
template<int OUTB>
__global__ __launch_bounds__(256) void k_ln(const u16* __restrict__ in, const float* __restrict__ gw,
                                            const float* __restrict__ bw, float* __restrict__ outf,
                                            u16* __restrict__ outb) {
  const int t = threadIdx.x, lane = t & 63, w = t >> 6;
  const long base = (long)blockIdx.x * D_;
  s4v xv = *(const s4v*)(in + base + t * 4);
  float v0 = b2f((u16)xv[0]), v1 = b2f((u16)xv[1]), v2 = b2f((u16)xv[2]), v3 = b2f((u16)xv[3]);
  float s = v0 + v1 + v2 + v3;
  float s2 = v0 * v0 + v1 * v1 + v2 * v2 + v3 * v3;
#pragma unroll
  for (int off = 1; off < 64; off <<= 1) { s += __shfl_xor(s, off); s2 += __shfl_xor(s2, off); }
  __shared__ float red[8];
  if (lane == 0) { red[w] = s; red[4 + w] = s2; }
  __syncthreads();
  s = red[0] + red[1] + red[2] + red[3];
  s2 = red[4] + red[5] + red[6] + red[7];
  float mu = s * (1.f / D_);
  float var = s2 * (1.f / D_) - mu * mu;
  float rstd = rsqrtf(var + 1e-6f);
  float4 gv = ((const float4*)gw)[t];
  float4 bv = ((const float4*)bw)[t];
  float o0 = (v0 - mu) * rstd * gv.x + bv.x;
  float o1 = (v1 - mu) * rstd * gv.y + bv.y;
  float o2 = (v2 - mu) * rstd * gv.z + bv.z;
  float o3 = (v3 - mu) * rstd * gv.w + bv.w;
  if constexpr (OUTB) {
    s4v o; o[0] = (short)f2b(o0); o[1] = (short)f2b(o1); o[2] = (short)f2b(o2); o[3] = (short)f2b(o3);
    *(s4v*)(outb + base + t * 4) = o;
  } else {
    float4 o; o.x = o0; o.y = o1; o.z = o2; o.w = o3;
    *(float4*)(outf + base + t * 4) = o;
  }
}

// ---------------- host ----------------

extern "C" void kernel_launch(void* const* d_in, const int* in_sizes, int n_in,
                              void* d_out, int out_size, void* d_ws, size_t ws_size,
                              hipStream_t stream) {
  const float* X      = (const float*)d_in[0];
  const float* Wq     = (const float*)d_in[1];
  const float* Wk     = (const float*)d_in[2];
  const float* Wv     = (const float*)d_in[3];
  const float* Wo     = (const float*)d_in[4];
  const float* g_attn = (const float*)d_in[5];
  const float* b_attn = (const float*)d_in[6];
  const float* W1     = (const float*)d_in[7];
  const float* b1     = (const float*)d_in[8];
  const float* W2     = (const float*)d_in[9];
  const float* b2     = (const float*)d_in[10];
  const float* g_ffn  = (const float*)d_in[11];
  const float* b_ffn  = (const float*)d_in[12];
  float* out = (float*)d_out;

  char* ws = (char*)d_ws;
  const size_t MB = 1ull << 20;
  u16* WqkvT = (u16*)(ws + 0 * MB);    // [3072][1024] bf16 (Wq|Wk|Wv transposed)
  u16* WoT   = (u16*)(ws + 6 * MB);    // [1024][1024]
  u16* W1T   = (u16*)(ws + 8 * MB);    // [4096][1024]
  u16* W2T   = (u16*)(ws + 16 * MB);   // [1024][4096]
  u16* Xb    = (u16*)(ws + 24 * MB);   // X bf16; later X1b
  u16* QKVb  = (u16*)(ws + 56 * MB);   // [16384][3072] = 96MB
  u16* Ab    = (u16*)(ws + 152 * MB);  // [16384][1024] = 32MB
  u16* Yb    = (u16*)(ws + 184 * MB);  // pre-LN buffers; end 216MB
  u16* Mid   = QKVb;                   // [16384][4096] = 128MB, reuses QKVb+Ab

  dim3 b256(256), b512(512);

  // single-launch weight prep (Wq gets DH^-0.5 = 0.125 folded in)
  WtJobs J;
  J.src[0] = Wq; J.src[1] = Wk; J.src[2] = Wv; J.src[3] = Wo; J.src[4] = W1; J.src[5] = W2;
  J.dst[0] = WqkvT; J.dst[1] = WqkvT + 1024 * 1024; J.dst[2] = WqkvT + 2048 * 1024;
  J.dst[3] = WoT; J.dst[4] = W1T; J.dst[5] = W2T;
  J.K[0] = 1024; J.K[1] = 1024; J.K[2] = 1024; J.K[3] = 1024; J.K[4] = 1024; J.K[5] = 4096;
  J.N[0] = 1024; J.N[1] = 1024; J.N[2] = 1024; J.N[3] = 1024; J.N[4] = 4096; J.N[5] = 1024;
  J.sc[0] = 0.125f; J.sc[1] = 1.f; J.sc[2] = 1.f; J.sc[3] = 1.f; J.sc[4] = 1.f; J.sc[5] = 1.f;
  J.off[0] = 0; J.off[1] = 1024; J.off[2] = 2048; J.off[3] = 3072;
  J.off[4] = 4096; J.off[5] = 8192; J.off[6] = 12288;
  k_wtall<<<dim3(12288), b256, 0, stream>>>(J);
  k_castx<<<dim3(16384), b256, 0, stream>>>(X, Xb);

  // fused QKV projection: [16384][3072]  (NB = 12)
  k_gemm256<0, 1024, 12><<<dim3(768), b512, 0, stream>>>(Xb, WqkvT, nullptr, nullptr, QKVb, 3072);
  // block-local attention
  k_attn<<<dim3(16, B_ * H_), b256, 0, stream>>>(QKVb, Ab);
  // Wo projection + residual bf16(X) from Xb (saves 32MB f32-res read; err <= 0.009)
  k_gemm256<1, 1024, 4><<<dim3(256), b512, 0, stream>>>(Ab, WoT, nullptr, Xb, Yb, 1024);
  // LN1 -> X1 (bf16)  (overwrites Xb AFTER Wo consumed it)
  k_ln<1><<<dim3(16384), b256, 0, stream>>>(Yb, g_attn, b_attn, nullptr, Xb);
  // FFN1: relu(X1@W1 + b1)  (NB = 16)
  k_gemm256<2, 1024, 16><<<dim3(1024), b512, 0, stream>>>(Xb, W1T, b1, nullptr, Mid, 4096);
  // FFN2: Mid@W2 + b2 + X1  (NB = 4)
  k_gemm256<3, 4096, 4><<<dim3(256), b512, 0, stream>>>(Mid, W2T, b2, Xb, Yb, 1024);
  // LN2 -> out (f32)
  k_ln<0><<<dim3(16384), b256, 0, stream>>>(Yb, g_ffn, b_ffn, out, nullptr);

  (void)in_sizes; (void)n_in; (void)out_size; (void)ws_size;
}